// Round 1
// baseline (209.009 us; speedup 1.0000x reference)
//
#include <hip/hip_runtime.h>

typedef unsigned short u16;
typedef __bf16 bf16x8 __attribute__((ext_vector_type(8)));
typedef float f32x4 __attribute__((ext_vector_type(4)));

#define H_HEADS 8
#define DHEAD 64
#define NSEQ 2048
#define DMODEL 512
#define BATCH 4
#define MROWS (BATCH * NSEQ)   // 8192

__device__ __forceinline__ u16 f2bf(float f) {
  unsigned u = __builtin_bit_cast(unsigned, f);
  u += 0x7fffu + ((u >> 16) & 1u);
  return (u16)(u >> 16);
}

__device__ __forceinline__ bf16x8 ldfrag(const u16* p) {
  return __builtin_bit_cast(bf16x8, *(const uint4*)p);
}

// ---------------- LayerNorm: x f32 [8192][512] -> xn bf16 ----------------
__global__ __launch_bounds__(256) void ln_kernel(
    const float* __restrict__ x, const float* __restrict__ g,
    const float* __restrict__ b, u16* __restrict__ xn) {
  const int row = blockIdx.x;
  const int t = threadIdx.x;
  const float2 v = *(const float2*)(x + (size_t)row * DMODEL + t * 2);
  float s = v.x + v.y;
  float ss = v.x * v.x + v.y * v.y;
  #pragma unroll
  for (int d = 1; d < 64; d <<= 1) {
    s += __shfl_xor(s, d);
    ss += __shfl_xor(ss, d);
  }
  __shared__ float red[8];
  const int wave = t >> 6, lane = t & 63;
  if (lane == 0) { red[wave] = s; red[4 + wave] = ss; }
  __syncthreads();
  s = red[0] + red[1] + red[2] + red[3];
  ss = red[4] + red[5] + red[6] + red[7];
  const float mean = s * (1.0f / DMODEL);
  const float var = ss * (1.0f / DMODEL) - mean * mean;
  const float rstd = rsqrtf(var + 1e-5f);
  const float2 gg = *(const float2*)(g + t * 2);
  const float2 bb = *(const float2*)(b + t * 2);
  const float o0 = (v.x - mean) * rstd * gg.x + bb.x;
  const float o1 = (v.y - mean) * rstd * gg.y + bb.y;
  const unsigned packed = (unsigned)f2bf(o0) | ((unsigned)f2bf(o1) << 16);
  *(unsigned*)(xn + (size_t)row * DMODEL + t * 2) = packed;
}

// ---------------- Weight transpose: W f32 [K=512][N=512] -> WT bf16 [N][K] ----------------
__global__ __launch_bounds__(256) void transpose_w_kernel(
    const float* __restrict__ W, u16* __restrict__ WT) {
  __shared__ float tile[32][33];
  const int n0 = blockIdx.x * 32, k0 = blockIdx.y * 32;
  const int t = threadIdx.x;
  #pragma unroll
  for (int p = 0; p < 4; ++p) {
    const int u = p * 256 + t;
    const int r = u >> 5, c = u & 31;
    tile[r][c] = W[(size_t)(k0 + r) * DMODEL + n0 + c];
  }
  __syncthreads();
  #pragma unroll
  for (int p = 0; p < 4; ++p) {
    const int u = p * 256 + t;
    const int rn = u >> 5, ck = u & 31;
    WT[(size_t)(n0 + rn) * DMODEL + k0 + ck] = f2bf(tile[ck][rn]);
  }
}

// ---------------- GEMM: C = A[M][K] * BT[N][K]^T + bias ----------------
// MODE 0: out bf16 in head layout [B][H][N][64], value = (acc+bias)*scale
// MODE 1: out f32 [M][N], value = acc + bias
#define LDK 72
template <int MODE>
__global__ __launch_bounds__(256) void gemm_kernel(
    const u16* __restrict__ A, const u16* __restrict__ BT,
    const float* __restrict__ bias, void* __restrict__ out,
    int M, int N, int K, float scale) {
  __shared__ u16 lds_a[64 * LDK];
  __shared__ u16 lds_b[64 * LDK];
  const int t = threadIdx.x;
  const int lane = t & 63, wave = t >> 6;
  const int wm = wave >> 1, wn = wave & 1;
  const int lo = lane & 15, hi = lane >> 4;
  const int m0 = blockIdx.y * 64, n0 = blockIdx.x * 64;
  f32x4 acc[2][2] = {};
  for (int k0 = 0; k0 < K; k0 += 64) {
    #pragma unroll
    for (int p = 0; p < 2; ++p) {
      const int u = p * 256 + t;
      const int row = u >> 3, ch = u & 7;
      *(uint4*)(lds_a + row * LDK + ch * 8) =
          *(const uint4*)(A + (size_t)(m0 + row) * K + k0 + ch * 8);
      *(uint4*)(lds_b + row * LDK + ch * 8) =
          *(const uint4*)(BT + (size_t)(n0 + row) * K + k0 + ch * 8);
    }
    __syncthreads();
    #pragma unroll
    for (int kc = 0; kc < 2; ++kc) {
      bf16x8 af[2], bfr[2];
      #pragma unroll
      for (int ms = 0; ms < 2; ++ms)
        af[ms] = ldfrag(lds_a + (wm * 32 + ms * 16 + lo) * LDK + kc * 32 + hi * 8);
      #pragma unroll
      for (int ns = 0; ns < 2; ++ns)
        bfr[ns] = ldfrag(lds_b + (wn * 32 + ns * 16 + lo) * LDK + kc * 32 + hi * 8);
      #pragma unroll
      for (int ms = 0; ms < 2; ++ms)
        #pragma unroll
        for (int ns = 0; ns < 2; ++ns)
          acc[ms][ns] = __builtin_amdgcn_mfma_f32_16x16x32_bf16(
              af[ms], bfr[ns], acc[ms][ns], 0, 0, 0);
    }
    __syncthreads();
  }
  #pragma unroll
  for (int ms = 0; ms < 2; ++ms) {
    #pragma unroll
    for (int ns = 0; ns < 2; ++ns) {
      const int col = n0 + wn * 32 + ns * 16 + lo;
      const float bi = bias[col];
      #pragma unroll
      for (int r = 0; r < 4; ++r) {
        const int row = m0 + wm * 32 + ms * 16 + hi * 4 + r;
        const float v = (acc[ms][ns][r] + bi) * scale;
        if (MODE == 0) {
          const int h = col >> 6, dk = col & 63;
          const int bb = row >> 11, seq = row & 2047;
          ((u16*)out)[(((size_t)(bb * H_HEADS + h) * NSEQ) + seq) * DHEAD + dk] = f2bf(v);
        } else {
          ((float*)out)[(size_t)row * DMODEL + col] = v;
        }
      }
    }
  }
}

// ---------------- V transpose: v bf16 [BH][N][64] -> vt bf16 [BH][64][N] ----------------
__global__ __launch_bounds__(256) void transpose_v_kernel(
    const u16* __restrict__ V, u16* __restrict__ VT) {
  __shared__ u16 tile[64 * LDK];
  const int bh = blockIdx.y, n0 = blockIdx.x * 64;
  const u16* Vh = V + (size_t)bh * NSEQ * DHEAD;
  u16* Oh = VT + (size_t)bh * DHEAD * NSEQ;
  const int t = threadIdx.x;
  #pragma unroll
  for (int p = 0; p < 2; ++p) {
    const int u = p * 256 + t;
    const int r = u >> 3, ch = u & 7;
    *(uint4*)(tile + r * LDK + ch * 8) =
        *(const uint4*)(Vh + (size_t)(n0 + r) * DHEAD + ch * 8);
  }
  __syncthreads();
  #pragma unroll
  for (int p = 0; p < 2; ++p) {
    const int u = p * 256 + t;
    const int dv = u >> 3, ch = u & 7;
    union { u16 s[8]; uint4 q; } tmp;
    #pragma unroll
    for (int j = 0; j < 8; ++j) tmp.s[j] = tile[(ch * 8 + j) * LDK + dv];
    *(uint4*)(Oh + (size_t)dv * NSEQ + n0 + ch * 8) = tmp.q;
  }
}

// ---------------- Flash attention (causal) ----------------
// Q [BH][N][64] bf16 (pre-scaled), K [BH][N][64] bf16, VT [BH][64][N] bf16
// O [B][N][512] bf16
__global__ __launch_bounds__(256) void attn_kernel(
    const u16* __restrict__ Q, const u16* __restrict__ K,
    const u16* __restrict__ VT, u16* __restrict__ O) {
  __shared__ u16 lds_k[64 * LDK];
  __shared__ u16 lds_vt[64 * LDK];
  __shared__ u16 lds_p[4 * 16 * LDK];
  const int t = threadIdx.x;
  const int lane = t & 63, wave = t >> 6;
  const int lo = lane & 15, hi = lane >> 4;
  const int bh = blockIdx.y, q0 = blockIdx.x * 64;
  const int b = bh >> 3, h = bh & 7;
  const u16* Qh = Q + (size_t)bh * NSEQ * DHEAD;
  const u16* Kh = K + (size_t)bh * NSEQ * DHEAD;
  const u16* Vh = VT + (size_t)bh * DHEAD * NSEQ;

  bf16x8 qf[2];
  const int qrow_f = q0 + wave * 16 + lo;
  #pragma unroll
  for (int c = 0; c < 2; ++c)
    qf[c] = ldfrag(Qh + (size_t)qrow_f * DHEAD + c * 32 + hi * 8);

  float m_r[4], l_r[4];
  f32x4 acc[4];
  #pragma unroll
  for (int r = 0; r < 4; ++r) { m_r[r] = -INFINITY; l_r[r] = 0.0f; }
  #pragma unroll
  for (int dt = 0; dt < 4; ++dt) acc[dt] = f32x4{0.f, 0.f, 0.f, 0.f};

  for (int kv0 = 0; kv0 <= q0; kv0 += 64) {
    #pragma unroll
    for (int p = 0; p < 2; ++p) {
      const int u = p * 256 + t;
      const int row = u >> 3, ch = u & 7;
      *(uint4*)(lds_k + row * LDK + ch * 8) =
          *(const uint4*)(Kh + (size_t)(kv0 + row) * DHEAD + ch * 8);
      *(uint4*)(lds_vt + row * LDK + ch * 8) =
          *(const uint4*)(Vh + (size_t)row * NSEQ + kv0 + ch * 8);
    }
    __syncthreads();

    // S = Q K^T for this wave's 16 q-rows x 64 kv-cols
    f32x4 s[4];
    #pragma unroll
    for (int tt = 0; tt < 4; ++tt) {
      f32x4 sa = {};
      #pragma unroll
      for (int c = 0; c < 2; ++c) {
        bf16x8 kf = ldfrag(lds_k + (tt * 16 + lo) * LDK + c * 32 + hi * 8);
        sa = __builtin_amdgcn_mfma_f32_16x16x32_bf16(qf[c], kf, sa, 0, 0, 0);
      }
      s[tt] = sa;
    }

    if (kv0 == q0) {  // diagonal tile: causal mask
      #pragma unroll
      for (int tt = 0; tt < 4; ++tt) {
        const int kvc = kv0 + tt * 16 + lo;
        #pragma unroll
        for (int r = 0; r < 4; ++r) {
          const int qr = q0 + wave * 16 + hi * 4 + r;
          if (kvc > qr) s[tt][r] = -1e30f;
        }
      }
    }

    // online softmax per row
    #pragma unroll
    for (int r = 0; r < 4; ++r) {
      float mx = fmaxf(fmaxf(s[0][r], s[1][r]), fmaxf(s[2][r], s[3][r]));
      #pragma unroll
      for (int d = 1; d < 16; d <<= 1) mx = fmaxf(mx, __shfl_xor(mx, d));
      const float mn = fmaxf(m_r[r], mx);
      const float sc = __expf(m_r[r] - mn);
      m_r[r] = mn;
      float ps = 0.0f;
      #pragma unroll
      for (int tt = 0; tt < 4; ++tt) {
        const float p = __expf(s[tt][r] - mn);
        s[tt][r] = p;
        ps += p;
      }
      #pragma unroll
      for (int d = 1; d < 16; d <<= 1) ps += __shfl_xor(ps, d);
      l_r[r] = l_r[r] * sc + ps;
      #pragma unroll
      for (int tt = 0; tt < 4; ++tt) acc[tt][r] *= sc;
    }

    // P -> LDS (bf16), then read back as A-frags
    u16* pbase = lds_p + wave * 16 * LDK;
    #pragma unroll
    for (int tt = 0; tt < 4; ++tt)
      #pragma unroll
      for (int r = 0; r < 4; ++r)
        pbase[(hi * 4 + r) * LDK + tt * 16 + lo] = f2bf(s[tt][r]);
    __syncthreads();

    bf16x8 pf[2];
    #pragma unroll
    for (int c = 0; c < 2; ++c)
      pf[c] = ldfrag(pbase + lo * LDK + c * 32 + hi * 8);
    #pragma unroll
    for (int dt = 0; dt < 4; ++dt) {
      #pragma unroll
      for (int c = 0; c < 2; ++c) {
        bf16x8 vf = ldfrag(lds_vt + (dt * 16 + lo) * LDK + c * 32 + hi * 8);
        acc[dt] = __builtin_amdgcn_mfma_f32_16x16x32_bf16(pf[c], vf, acc[dt], 0, 0, 0);
      }
    }
    __syncthreads();
  }

  const int qr_out = q0 + wave * 16 + hi * 4;
  #pragma unroll
  for (int dt = 0; dt < 4; ++dt) {
    #pragma unroll
    for (int r = 0; r < 4; ++r) {
      const float v = acc[dt][r] / l_r[r];
      O[((size_t)b * NSEQ + qr_out + r) * DMODEL + h * DHEAD + dt * 16 + lo] = f2bf(v);
    }
  }
}

// ---------------- host ----------------
extern "C" void kernel_launch(void* const* d_in, const int* in_sizes, int n_in,
                              void* d_out, int out_size, void* d_ws, size_t ws_size,
                              hipStream_t stream) {
  const float* x = (const float*)d_in[0];
  // d_in[1] = attn_mask (causal, applied analytically)
  const float* ln_g = (const float*)d_in[2];
  const float* ln_b = (const float*)d_in[3];
  const float* wq = (const float*)d_in[4];
  const float* bq = (const float*)d_in[5];
  const float* wk = (const float*)d_in[6];
  const float* bk = (const float*)d_in[7];
  const float* wv = (const float*)d_in[8];
  const float* bv = (const float*)d_in[9];
  const float* wo = (const float*)d_in[10];
  const float* bo = (const float*)d_in[11];

  char* ws = (char*)d_ws;
  u16* xn = (u16*)ws;            ws += (size_t)MROWS * DMODEL * 2;
  u16* wqT = (u16*)ws;           ws += (size_t)DMODEL * DMODEL * 2;
  u16* wkT = (u16*)ws;           ws += (size_t)DMODEL * DMODEL * 2;
  u16* wvT = (u16*)ws;           ws += (size_t)DMODEL * DMODEL * 2;
  u16* woT = (u16*)ws;           ws += (size_t)DMODEL * DMODEL * 2;
  u16* qb = (u16*)ws;            ws += (size_t)MROWS * DMODEL * 2;
  u16* kb = (u16*)ws;            ws += (size_t)MROWS * DMODEL * 2;
  u16* vb = (u16*)ws;            ws += (size_t)MROWS * DMODEL * 2;
  u16* vtb = (u16*)ws;           ws += (size_t)MROWS * DMODEL * 2;
  u16* attnb = (u16*)ws;         ws += (size_t)MROWS * DMODEL * 2;

  ln_kernel<<<MROWS, 256, 0, stream>>>(x, ln_g, ln_b, xn);
  transpose_w_kernel<<<dim3(16, 16), 256, 0, stream>>>(wq, wqT);
  transpose_w_kernel<<<dim3(16, 16), 256, 0, stream>>>(wk, wkT);
  transpose_w_kernel<<<dim3(16, 16), 256, 0, stream>>>(wv, wvT);
  transpose_w_kernel<<<dim3(16, 16), 256, 0, stream>>>(wo, woT);

  const float qscale = 0.125f;  // DK^-0.5
  gemm_kernel<0><<<dim3(DMODEL / 64, MROWS / 64), 256, 0, stream>>>(
      xn, wqT, bq, qb, MROWS, DMODEL, DMODEL, qscale);
  gemm_kernel<0><<<dim3(DMODEL / 64, MROWS / 64), 256, 0, stream>>>(
      xn, wkT, bk, kb, MROWS, DMODEL, DMODEL, 1.0f);
  gemm_kernel<0><<<dim3(DMODEL / 64, MROWS / 64), 256, 0, stream>>>(
      xn, wvT, bv, vb, MROWS, DMODEL, DMODEL, 1.0f);

  transpose_v_kernel<<<dim3(NSEQ / 64, BATCH * H_HEADS), 256, 0, stream>>>(vb, vtb);

  attn_kernel<<<dim3(NSEQ / 64, BATCH * H_HEADS), 256, 0, stream>>>(qb, kb, vtb, attnb);

  gemm_kernel<1><<<dim3(DMODEL / 64, MROWS / 64), 256, 0, stream>>>(
      attnb, woT, bo, d_out, MROWS, DMODEL, DMODEL, 1.0f);
}

// Round 2
// 139.749 us; speedup vs baseline: 1.4956x; 1.4956x over previous
//
#include <hip/hip_runtime.h>

typedef unsigned short u16;
typedef __bf16 bf16x8 __attribute__((ext_vector_type(8)));
typedef float f32x4 __attribute__((ext_vector_type(4)));

#define H_HEADS 8
#define DHEAD 64
#define NSEQ 2048
#define DMODEL 512
#define BATCH 4
#define MROWS (BATCH * NSEQ)   // 8192
#define BH (BATCH * H_HEADS)   // 32

__device__ __forceinline__ u16 f2bf(float f) {
  unsigned u = __builtin_bit_cast(unsigned, f);
  u += 0x7fffu + ((u >> 16) & 1u);
  return (u16)(u >> 16);
}

__device__ __forceinline__ bf16x8 ldfrag(const u16* p) {
  return __builtin_bit_cast(bf16x8, *(const uint4*)p);
}

typedef __attribute__((address_space(1))) void GV;
typedef __attribute__((address_space(3))) void LV;
__device__ __forceinline__ void gld16(const void* g, void* l) {
  __builtin_amdgcn_global_load_lds((GV*)g, (LV*)l, 16, 0, 0);
}

// ---------------- LayerNorm: x f32 [8192][512] -> xn bf16 ----------------
__global__ __launch_bounds__(256) void ln_kernel(
    const float* __restrict__ x, const float* __restrict__ g,
    const float* __restrict__ b, u16* __restrict__ xn) {
  const int row = blockIdx.x;
  const int t = threadIdx.x;
  const float2 v = *(const float2*)(x + (size_t)row * DMODEL + t * 2);
  float s = v.x + v.y;
  float ss = v.x * v.x + v.y * v.y;
  #pragma unroll
  for (int d = 1; d < 64; d <<= 1) {
    s += __shfl_xor(s, d);
    ss += __shfl_xor(ss, d);
  }
  __shared__ float red[8];
  const int wave = t >> 6, lane = t & 63;
  if (lane == 0) { red[wave] = s; red[4 + wave] = ss; }
  __syncthreads();
  s = red[0] + red[1] + red[2] + red[3];
  ss = red[4] + red[5] + red[6] + red[7];
  const float mean = s * (1.0f / DMODEL);
  const float var = ss * (1.0f / DMODEL) - mean * mean;
  const float rstd = rsqrtf(var + 1e-5f);
  const float2 gg = *(const float2*)(g + t * 2);
  const float2 bb = *(const float2*)(b + t * 2);
  const float o0 = (v.x - mean) * rstd * gg.x + bb.x;
  const float o1 = (v.y - mean) * rstd * gg.y + bb.y;
  const unsigned packed = (unsigned)f2bf(o0) | ((unsigned)f2bf(o1) << 16);
  *(unsigned*)(xn + (size_t)row * DMODEL + t * 2) = packed;
}

// ---------------- Weight transpose: W f32 [K=512][N=512] -> WT bf16 [N][K] ----------------
__global__ __launch_bounds__(256) void transpose_w_kernel(
    const float* __restrict__ W, u16* __restrict__ WT) {
  __shared__ float tile[32][33];
  const int n0 = blockIdx.x * 32, k0 = blockIdx.y * 32;
  const int t = threadIdx.x;
  #pragma unroll
  for (int p = 0; p < 4; ++p) {
    const int u = p * 256 + t;
    const int r = u >> 5, c = u & 31;
    tile[r][c] = W[(size_t)(k0 + r) * DMODEL + n0 + c];
  }
  __syncthreads();
  #pragma unroll
  for (int p = 0; p < 4; ++p) {
    const int u = p * 256 + t;
    const int rn = u >> 5, ck = u & 31;
    WT[(size_t)(n0 + rn) * DMODEL + k0 + ck] = f2bf(tile[ck][rn]);
  }
}

// ---------------- V transpose: v bf16 [BH][N][64] -> vt bf16 [BH][64][N] ----------------
#define LDK 72
__global__ __launch_bounds__(256) void transpose_v_kernel(
    const u16* __restrict__ V, u16* __restrict__ VT) {
  __shared__ u16 tile[64 * LDK];
  const int bh = blockIdx.y, n0 = blockIdx.x * 64;
  const u16* Vh = V + (size_t)bh * NSEQ * DHEAD;
  u16* Oh = VT + (size_t)bh * DHEAD * NSEQ;
  const int t = threadIdx.x;
  #pragma unroll
  for (int p = 0; p < 2; ++p) {
    const int u = p * 256 + t;
    const int r = u >> 3, ch = u & 7;
    *(uint4*)(tile + r * LDK + ch * 8) =
        *(const uint4*)(Vh + (size_t)(n0 + r) * DHEAD + ch * 8);
  }
  __syncthreads();
  #pragma unroll
  for (int p = 0; p < 2; ++p) {
    const int u = p * 256 + t;
    const int dv = u >> 3, ch = u & 7;
    union { u16 s[8]; uint4 q; } tmp;
    #pragma unroll
    for (int j = 0; j < 8; ++j) tmp.s[j] = tile[(ch * 8 + j) * LDK + dv];
    *(uint4*)(Oh + (size_t)dv * NSEQ + n0 + ch * 8) = tmp.q;
  }
}

// ---------------- GEMM 128x128, BK=64, global_load_lds, XOR-swizzled LDS ----------------
// MODE 0: fused QKV. A=xn[8192][512], BT=wqkvT[1536][512]. Writes q/k/v head layout bf16.
// MODE 1: out proj. A=attnb[8192][512], BT=woT[512][512]. Writes f32 [8192][512]+bias.
template <int MODE>
__global__ __launch_bounds__(256) void gemm128_kernel(
    const u16* __restrict__ A, const u16* __restrict__ BT,
    const float* __restrict__ bq, const float* __restrict__ bk,
    const float* __restrict__ bv,
    u16* __restrict__ qb, u16* __restrict__ kb, u16* __restrict__ vb,
    float* __restrict__ fout, int K) {
  __shared__ u16 lds_a[128 * 64];
  __shared__ u16 lds_b[128 * 64];
  const int t = threadIdx.x;
  const int lane = t & 63, wave = t >> 6;
  const int wm = wave >> 1, wn = wave & 1;
  const int lo = lane & 15, hi = lane >> 4;
  const int m0 = blockIdx.y * 128, n0 = blockIdx.x * 128;
  const int sr = lane >> 3;                       // staging row-in-chunk 0..7
  const int scol = (((lane & 7) ^ sr) * 8);       // pre-swizzled source col (elems)
  f32x4 acc[4][4] = {};
  for (int k0 = 0; k0 < K; k0 += 64) {
    #pragma unroll
    for (int j = 0; j < 4; ++j) {
      const int ch = wave * 4 + j;  // 16 chunks of 8 rows
      gld16(A + (size_t)(m0 + ch * 8 + sr) * K + k0 + scol, lds_a + ch * 512);
      gld16(BT + (size_t)(n0 + ch * 8 + sr) * K + k0 + scol, lds_b + ch * 512);
    }
    __syncthreads();
    #pragma unroll
    for (int kc = 0; kc < 2; ++kc) {
      bf16x8 af[4], bfr[4];
      const int sw = ((lo & 7) * 8);
      #pragma unroll
      for (int i = 0; i < 4; ++i)
        af[i] = ldfrag(lds_a + (wm * 64 + i * 16 + lo) * 64 + ((kc * 32 + hi * 8) ^ sw));
      #pragma unroll
      for (int i = 0; i < 4; ++i)
        bfr[i] = ldfrag(lds_b + (wn * 64 + i * 16 + lo) * 64 + ((kc * 32 + hi * 8) ^ sw));
      __builtin_amdgcn_s_setprio(1);
      #pragma unroll
      for (int mi = 0; mi < 4; ++mi)
        #pragma unroll
        for (int ni = 0; ni < 4; ++ni)
          acc[mi][ni] = __builtin_amdgcn_mfma_f32_16x16x32_bf16(
              af[mi], bfr[ni], acc[mi][ni], 0, 0, 0);
      __builtin_amdgcn_s_setprio(0);
    }
    __syncthreads();
  }
  #pragma unroll
  for (int mi = 0; mi < 4; ++mi) {
    #pragma unroll
    for (int ni = 0; ni < 4; ++ni) {
      const int col = n0 + wn * 64 + ni * 16 + lo;
      if (MODE == 0) {
        const int mat = col >> 9, w = col & 511;
        const int hh = w >> 6, dk = w & 63;
        const float bi = (mat == 0 ? bq : (mat == 1 ? bk : bv))[w];
        const float sc = (mat == 0) ? 0.125f : 1.0f;
        u16* dst = (mat == 0 ? qb : (mat == 1 ? kb : vb));
        #pragma unroll
        for (int r = 0; r < 4; ++r) {
          const int row = m0 + wm * 64 + mi * 16 + hi * 4 + r;
          const int bbx = row >> 11, seq = row & 2047;
          dst[(((size_t)(bbx * H_HEADS + hh) * NSEQ) + seq) * DHEAD + dk] =
              f2bf((acc[mi][ni][r] + bi) * sc);
        }
      } else {
        const float bi = bq[col];
        #pragma unroll
        for (int r = 0; r < 4; ++r) {
          const int row = m0 + wm * 64 + mi * 16 + hi * 4 + r;
          fout[(size_t)row * DMODEL + col] = acc[mi][ni][r] + bi;
        }
      }
    }
  }
}

// ---------------- Flash attention (causal, balanced pairing, dbuf prefetch) ----------------
// Q [BH][N][64] bf16 (pre-scaled), K [BH][N][64] bf16, VT [BH][64][N] bf16
// O [B][N][512] bf16.  Block b handles q-tiles {b, 31-b}: 33 kv-iters each block.
__global__ __launch_bounds__(256) void attn_kernel(
    const u16* __restrict__ Q, const u16* __restrict__ K,
    const u16* __restrict__ VT, u16* __restrict__ O) {
  __shared__ u16 lds_k[2][64 * 64];
  __shared__ u16 lds_v[2][64 * 64];
  __shared__ u16 lds_p[4 * 16 * LDK];
  const int t = threadIdx.x;
  const int lane = t & 63, wave = t >> 6;
  const int lo = lane & 15, hi = lane >> 4;
  const int bh = blockIdx.y;
  const int b = bh >> 3, h = bh & 7;
  const u16* Qh = Q + (size_t)bh * NSEQ * DHEAD;
  const u16* Kh = K + (size_t)bh * NSEQ * DHEAD;
  const u16* Vh = VT + (size_t)bh * DHEAD * NSEQ;
  const int sr = lane >> 3;
  const int scol = (((lane & 7) ^ sr) * 8);   // pre-swizzled source col (elems)
  u16* pbase = lds_p + wave * 16 * LDK;

  for (int half = 0; half < 2; ++half) {
    const int qt = half ? (31 - (int)blockIdx.x) : (int)blockIdx.x;
    const int q0 = qt * 64;
    const int nt = qt + 1;

    bf16x8 qf[2];
    {
      const int qr = q0 + wave * 16 + lo;
      qf[0] = ldfrag(Qh + (size_t)qr * DHEAD + hi * 8);
      qf[1] = ldfrag(Qh + (size_t)qr * DHEAD + 32 + hi * 8);
    }
    float m_r[4], l_r[4];
    f32x4 acc[4];
    #pragma unroll
    for (int r = 0; r < 4; ++r) { m_r[r] = -INFINITY; l_r[r] = 0.0f; }
    #pragma unroll
    for (int dt = 0; dt < 4; ++dt) acc[dt] = f32x4{0.f, 0.f, 0.f, 0.f};

    // prologue: stage kv-tile 0 into buf 0 (4 gld16 per thread)
    #pragma unroll
    for (int j = 0; j < 2; ++j) {
      const int ch = wave * 2 + j;  // 8 chunks of 8 rows
      gld16(Kh + (size_t)(ch * 8 + sr) * DHEAD + scol, lds_k[0] + ch * 512);
      gld16(Vh + (size_t)(ch * 8 + sr) * NSEQ + scol, lds_v[0] + ch * 512);
    }

    for (int kt = 0; kt < nt; ++kt) {
      const int cur = kt & 1;
      if (kt + 1 < nt) {
        const int kvn = (kt + 1) * 64;
        #pragma unroll
        for (int j = 0; j < 2; ++j) {
          const int ch = wave * 2 + j;
          gld16(Kh + (size_t)(kvn + ch * 8 + sr) * DHEAD + scol, lds_k[cur ^ 1] + ch * 512);
          gld16(Vh + (size_t)(ch * 8 + sr) * NSEQ + kvn + scol, lds_v[cur ^ 1] + ch * 512);
        }
        asm volatile("s_waitcnt vmcnt(4)" ::: "memory");
      } else {
        asm volatile("s_waitcnt vmcnt(0)" ::: "memory");
      }
      __builtin_amdgcn_s_barrier();
      __builtin_amdgcn_sched_barrier(0);

      const u16* lk = lds_k[cur];
      const u16* lv = lds_v[cur];
      const int sw = ((lo & 7) * 8);

      // S = Q K^T : 16 q-rows x 64 kv
      f32x4 s[4];
      #pragma unroll
      for (int tt = 0; tt < 4; ++tt) {
        f32x4 sa = {};
        __builtin_amdgcn_s_setprio(1);
        #pragma unroll
        for (int c = 0; c < 2; ++c) {
          bf16x8 kf = ldfrag(lk + (tt * 16 + lo) * 64 + ((c * 32 + hi * 8) ^ sw));
          sa = __builtin_amdgcn_mfma_f32_16x16x32_bf16(qf[c], kf, sa, 0, 0, 0);
        }
        __builtin_amdgcn_s_setprio(0);
        s[tt] = sa;
      }

      if (kt == nt - 1) {  // diagonal tile: causal mask
        #pragma unroll
        for (int tt = 0; tt < 4; ++tt) {
          const int kvc = q0 + tt * 16 + lo;
          #pragma unroll
          for (int r = 0; r < 4; ++r) {
            const int qr = q0 + wave * 16 + hi * 4 + r;
            if (kvc > qr) s[tt][r] = -1e30f;
          }
        }
      }

      // online softmax per q-row (16-lane groups)
      #pragma unroll
      for (int r = 0; r < 4; ++r) {
        float mx = fmaxf(fmaxf(s[0][r], s[1][r]), fmaxf(s[2][r], s[3][r]));
        #pragma unroll
        for (int d = 1; d < 16; d <<= 1) mx = fmaxf(mx, __shfl_xor(mx, d));
        const float mn = fmaxf(m_r[r], mx);
        const float sc = __expf(m_r[r] - mn);
        m_r[r] = mn;
        float ps = 0.0f;
        #pragma unroll
        for (int tt = 0; tt < 4; ++tt) {
          const float p = __expf(s[tt][r] - mn);
          s[tt][r] = p;
          ps += p;
        }
        #pragma unroll
        for (int d = 1; d < 16; d <<= 1) ps += __shfl_xor(ps, d);
        l_r[r] = l_r[r] * sc + ps;
        #pragma unroll
        for (int tt = 0; tt < 4; ++tt) acc[tt][r] *= sc;
      }

      // P -> per-wave LDS (same-wave DS ordering; no barrier needed)
      #pragma unroll
      for (int tt = 0; tt < 4; ++tt)
        #pragma unroll
        for (int r = 0; r < 4; ++r)
          pbase[(hi * 4 + r) * LDK + tt * 16 + lo] = f2bf(s[tt][r]);

      bf16x8 pf[2];
      #pragma unroll
      for (int c = 0; c < 2; ++c)
        pf[c] = ldfrag(pbase + lo * LDK + c * 32 + hi * 8);
      #pragma unroll
      for (int dt = 0; dt < 4; ++dt) {
        __builtin_amdgcn_s_setprio(1);
        #pragma unroll
        for (int c = 0; c < 2; ++c) {
          bf16x8 vf = ldfrag(lv + (dt * 16 + lo) * 64 + ((c * 32 + hi * 8) ^ sw));
          acc[dt] = __builtin_amdgcn_mfma_f32_16x16x32_bf16(pf[c], vf, acc[dt], 0, 0, 0);
        }
        __builtin_amdgcn_s_setprio(0);
      }
      __builtin_amdgcn_sched_barrier(0);
      __builtin_amdgcn_s_barrier();   // protect buf[cur] before next-iter overwrite
      __builtin_amdgcn_sched_barrier(0);
    }

    // epilogue: O = acc / l
    const int qrow = q0 + wave * 16 + hi * 4;
    #pragma unroll
    for (int dt = 0; dt < 4; ++dt) {
      #pragma unroll
      for (int r = 0; r < 4; ++r) {
        const float v = acc[dt][r] / l_r[r];
        O[((size_t)b * NSEQ + qrow + r) * DMODEL + h * DHEAD + dt * 16 + lo] = f2bf(v);
      }
    }
  }
}

// ---------------- host ----------------
extern "C" void kernel_launch(void* const* d_in, const int* in_sizes, int n_in,
                              void* d_out, int out_size, void* d_ws, size_t ws_size,
                              hipStream_t stream) {
  const float* x = (const float*)d_in[0];
  // d_in[1] = attn_mask (causal, applied analytically)
  const float* ln_g = (const float*)d_in[2];
  const float* ln_b = (const float*)d_in[3];
  const float* wq = (const float*)d_in[4];
  const float* bq = (const float*)d_in[5];
  const float* wk = (const float*)d_in[6];
  const float* bk = (const float*)d_in[7];
  const float* wv = (const float*)d_in[8];
  const float* bv = (const float*)d_in[9];
  const float* wo = (const float*)d_in[10];
  const float* bo = (const float*)d_in[11];

  char* ws = (char*)d_ws;
  u16* xn = (u16*)ws;     ws += (size_t)MROWS * DMODEL * 2;
  u16* wqkvT = (u16*)ws;  ws += (size_t)3 * DMODEL * DMODEL * 2;
  u16* woT = (u16*)ws;    ws += (size_t)DMODEL * DMODEL * 2;
  u16* qb = (u16*)ws;     ws += (size_t)MROWS * DMODEL * 2;
  u16* kb = (u16*)ws;     ws += (size_t)MROWS * DMODEL * 2;
  u16* vb = (u16*)ws;     ws += (size_t)MROWS * DMODEL * 2;
  u16* vtb = (u16*)ws;    ws += (size_t)MROWS * DMODEL * 2;
  u16* attnb = (u16*)ws;  ws += (size_t)MROWS * DMODEL * 2;

  ln_kernel<<<MROWS, 256, 0, stream>>>(x, ln_g, ln_b, xn);
  transpose_w_kernel<<<dim3(16, 16), 256, 0, stream>>>(wq, wqkvT);
  transpose_w_kernel<<<dim3(16, 16), 256, 0, stream>>>(wk, wqkvT + (size_t)DMODEL * DMODEL);
  transpose_w_kernel<<<dim3(16, 16), 256, 0, stream>>>(wv, wqkvT + (size_t)2 * DMODEL * DMODEL);
  transpose_w_kernel<<<dim3(16, 16), 256, 0, stream>>>(wo, woT);

  // fused QKV: M=8192, N=1536, K=512
  gemm128_kernel<0><<<dim3(12, 64), 256, 0, stream>>>(
      xn, wqkvT, bq, bk, bv, qb, kb, vb, nullptr, DMODEL);

  transpose_v_kernel<<<dim3(NSEQ / 64, BH), 256, 0, stream>>>(vb, vtb);

  attn_kernel<<<dim3(16, BH), 256, 0, stream>>>(qb, kb, vtb, attnb);

  // out proj: M=8192, N=512, K=512 (f32 out)
  gemm128_kernel<1><<<dim3(4, 64), 256, 0, stream>>>(
      attnb, woT, bo, nullptr, nullptr, nullptr, nullptr, nullptr,
      (float*)d_out, DMODEL);
}